// Round 8
// baseline (586.125 us; speedup 1.0000x reference)
//
#include <hip/hip_runtime.h>
#include <hip/hip_bf16.h>

#define NS    32768    // samples
#define NA    1024     // atoms
#define AL    2048     // atom length
#define KKEEP 1024     // top-k
#define CAPC  (512*1024)

struct Cand { float v; unsigned idx; };

typedef short  short8  __attribute__((ext_vector_type(8)));
typedef short  short4v __attribute__((ext_vector_type(4)));
typedef float  f32x4   __attribute__((ext_vector_type(4)));

// ---------------------------------------------------------------------------
// ws layout (bytes):
//   0       : float hdr[3]  { sumsq x[b=0], sumsq x[b=1], sumsq atoms }
//   16      : unsigned candCnt[2]
//   64      : Cand sel[2][KKEEP]                  (16 KB)
//   65536   : unsigned short ab16[1024*2048]      (4 MB, bf16 atoms)
//   4259840 : Cand cand[2][cap]
// ---------------------------------------------------------------------------

__device__ inline unsigned short f2bf(float f) {
    union { float f; unsigned u; } v; v.f = f;
    unsigned r = v.u + 0x7fffu + ((v.u >> 16) & 1u);   // round-to-nearest-even
    return (unsigned short)(r >> 16);
}

__global__ void sums_kernel(const float* __restrict__ x, const float* __restrict__ atoms,
                            float* __restrict__ hdr) {
    const long total = 2L*NS + (long)NA*AL;
    float sx0 = 0.f, sx1 = 0.f, sa = 0.f;
    for (long i = (long)blockIdx.x*blockDim.x + threadIdx.x; i < total;
         i += (long)gridDim.x*blockDim.x) {
        if (i < NS)        { float v = x[i];            sx0 += v*v; }
        else if (i < 2*NS) { float v = x[i];            sx1 += v*v; }
        else               { float v = atoms[i - 2*NS]; sa  += v*v; }
    }
    #pragma unroll
    for (int o = 32; o >= 1; o >>= 1) {
        sx0 += __shfl_down(sx0, o);
        sx1 += __shfl_down(sx1, o);
        sa  += __shfl_down(sa , o);
    }
    if ((threadIdx.x & 63) == 0) {
        if (sx0 != 0.f) atomicAdd(&hdr[0], sx0);
        if (sx1 != 0.f) atomicAdd(&hdr[1], sx1);
        if (sa  != 0.f) atomicAdd(&hdr[2], sa);
    }
}

__global__ void cvt_atoms_kernel(const float* __restrict__ atoms,
                                 unsigned short* __restrict__ ab16) {
    int i = (blockIdx.x * 256 + threadIdx.x) * 4;     // grid covers 2M elems
    float4 f = *(const float4*)(atoms + i);
    ushort4 o;
    o.x = f2bf(f.x); o.y = f2bf(f.y); o.z = f2bf(f.z); o.w = f2bf(f.w);
    *(ushort4*)(ab16 + i) = o;
}

// ---------------------------------------------------------------------------
// MFMA fm kernel — 256x256 tile, 8 waves (2m x 4n), wave tile 128x64,
// 8-phase-style schedule (4 phases per BK=64 chunk):
//   phase = { 4x ds_read_b128 A-frags | 1x global_load_lds quarter-stage of
//             chunk c+2 | s_barrier | setprio1 + 16 MFMA + setprio0 |
//             (ROLLB / wrap / vmcnt(4)) | s_barrier }
// Triple-buffered A (3x32KB) -> staging runs 2 chunks ahead; ONE counted
// s_waitcnt vmcnt(4) per chunk (never 0 in-loop); raw s_barrier only.
//
// B operand (x Toeplitz) from REVERSED bf16 x-window in LDS:
// frag elem j = xr[R+j], R(ni,S) = Rbase - 16*ni + 32*S,
// Rbase = 255 - wn*64 - ln + 8*g, xr[p] = x[t0+255-p].
// Rolling identity: frag(ni,S+1) = frag(ni-2,S) -> only ni=0,1 fresh/k-step.
// 4 shifted copies (p=(R+3)&~3, m=p-R, stride 4640 B == 32 mod 128):
// each B-frag = two 8B-aligned ds_read_b64, conflict-free.
// A tile staged via global_load_lds(16B), XOR swizzle folded into the
// per-lane GLOBAL source address (LDS dest linear); read back with
// blk' = blk ^ (row&7) -> conflict-free ds_read_b128 (2-way rows, free).
// K-chunk order rotated per block ((c+rot)&31) to de-convoy L2.
// ---------------------------------------------------------------------------
#define XRW      2303      // reversed-window elements: [t0-2047 .. t0+255]
#define XRSTRIDE 2320      // elems per copy (4640 B: mult of 8, == 32 mod 128)
#define XRB      4640
#define NCPY     4
#define SA_BUF   32768     // bytes per A buffer (256 rows x 8 blk x 16B)

__device__ inline void gload_lds16(const unsigned short* g, unsigned char* lds) {
    __builtin_amdgcn_global_load_lds((const __attribute__((address_space(1))) void*)g,
                                     (__attribute__((address_space(3))) void*)lds,
                                     16, 0, 0);
}

__global__ __launch_bounds__(512, 2)
void fm_kernel(const float* __restrict__ x, const unsigned short* __restrict__ ab16,
               const float* __restrict__ hdr, unsigned* __restrict__ candCnt,
               Cand* __restrict__ cand, unsigned cap)
{
    __shared__ __align__(16) unsigned char  sA[3 * SA_BUF];
    __shared__ __align__(16) unsigned short sXR[NCPY * XRSTRIDE];

    const int bid = blockIdx.x;
    const int b   = bid >> 9;           // grid = 2 * 4 * 128
    const int rem = bid & 511;
    const int a0  = (rem >> 7) * 256;
    const int t0  = (rem & 127) * 256;

    const int tid  = threadIdx.x;
    const int lane = tid & 63;
    const int wid  = tid >> 6;          // 0..7
    const int wm   = wid >> 2;          // 0..1 (m 128-block)
    const int wn   = wid & 3;           // 0..3 (n 64-block)
    const int g    = lane >> 4;         // k-group 0..3
    const int ln   = lane & 15;

    const int rot = (bid * 5) & 31;     // per-block K-chunk rotation

    const float* __restrict__ xb = x + b * NS;

    // ---- stage reversed x window as bf16, 4 shifted copies ----
    for (int ti = tid; ti < XRW; ti += 512) {
        int t = t0 - 2047 + ti;
        float f = (t >= 0) ? xb[t] : 0.f;         // t < NS always
        unsigned short h = f2bf(f);
        int p0 = 2302 - ti;                       // xr[p] = x[t0+255-p]
        #pragma unroll
        for (int m = 0; m < NCPY; ++m) sXR[m * XRSTRIDE + p0 + m] = h;
    }

    // one quarter-stage of A chunk `ck` into buffer at byte base `bfB`
    #define STAGE1(bfB, ck, q) do {                                              \
        int slot = (q) * 512 + tid;                                              \
        int row  = slot >> 3;                                                    \
        int blk  = slot & 7;                                                     \
        const unsigned short* gsrc =                                             \
            ab16 + (size_t)(a0 + row) * AL + (ck) * 64 + ((blk ^ (row & 7)) << 3); \
        gload_lds16(gsrc, sA + (bfB) + ((q) * 512 + wid * 64) * 16);             \
    } while (0)

    f32x4 acc[8][4];
    #pragma unroll
    for (int i = 0; i < 8; ++i)
        #pragma unroll
        for (int j = 0; j < 4; ++j) acc[i][j] = (f32x4)0.0f;

    // lane-constant base: R(ni,S) = Rbase - 16*ni + 32*S
    const int Rbase = 255 - wn * 64 - ln + 8 * g;
    const unsigned char* xrb = (const unsigned char*)sXR;
    const unsigned char* sAp = (const unsigned char*)sA;

    // lane-constant A-read offsets (row&7 == ln&7)
    int rowoff[8];
    #pragma unroll
    for (int mi = 0; mi < 8; ++mi) rowoff[mi] = (wm * 128 + mi * 16 + ln) * 128;
    const int swz0 = ((0 * 4 + g) ^ (ln & 7)) << 4;   // s=0 swizzled blk byte-off
    const int swz1 = ((1 * 4 + g) ^ (ln & 7)) << 4;   // s=1

    // loadB(R): p = (R+3)&~3 (8B-aligned slot), copy m = p-R, two b64 reads
    #define LOADB(Rv, dst) do {                                                 \
        int p_ = ((Rv) + 3) & ~3;                                               \
        const unsigned char* a_ =                                               \
            xrb + (unsigned)(p_ - (Rv)) * XRB + (unsigned)p_ * 2u;              \
        short4v lo_ = *(const short4v*)a_;                                      \
        short4v hi_ = *(const short4v*)(a_ + 8);                                \
        dst = __builtin_shufflevector(lo_, hi_, 0, 1, 2, 3, 4, 5, 6, 7);        \
    } while (0)

    short8 b0, b1, b2, b3;

    #define LOADB4(Sv) do {                        \
        LOADB(Rbase      + 32 * (Sv), b0);         \
        LOADB(Rbase - 16 + 32 * (Sv), b1);         \
        LOADB(Rbase - 32 + 32 * (Sv), b2);         \
        LOADB(Rbase - 48 + 32 * (Sv), b3);         \
    } while (0)

    // frag(ni,S+1) = frag(ni-2,S): shift chain + 2 fresh
    #define ROLLB(Sv) do {                         \
        b3 = b1; b2 = b0;                          \
        LOADB(Rbase      + 32 * (Sv), b0);         \
        LOADB(Rbase - 16 + 32 * (Sv), b1);         \
    } while (0)

    // one phase: 4 A-frag reads + 1 quarter-stage + bar + 16 MFMA + EXTRA + bar
    #define PHASE(m0, soff, q, EXTRA) do {                                              \
        short8 af0 = *(const short8*)(sAp + curBase + (soff) + rowoff[(m0)+0]);         \
        short8 af1 = *(const short8*)(sAp + curBase + (soff) + rowoff[(m0)+1]);         \
        short8 af2 = *(const short8*)(sAp + curBase + (soff) + rowoff[(m0)+2]);         \
        short8 af3 = *(const short8*)(sAp + curBase + (soff) + rowoff[(m0)+3]);         \
        STAGE1(stBase, stChunk, q);                                                     \
        __builtin_amdgcn_s_barrier();                                                   \
        __builtin_amdgcn_s_setprio(1);                                                  \
        acc[(m0)+0][0] = __builtin_amdgcn_mfma_f32_16x16x32_bf16(af0, b0, acc[(m0)+0][0],0,0,0); \
        acc[(m0)+0][1] = __builtin_amdgcn_mfma_f32_16x16x32_bf16(af0, b1, acc[(m0)+0][1],0,0,0); \
        acc[(m0)+0][2] = __builtin_amdgcn_mfma_f32_16x16x32_bf16(af0, b2, acc[(m0)+0][2],0,0,0); \
        acc[(m0)+0][3] = __builtin_amdgcn_mfma_f32_16x16x32_bf16(af0, b3, acc[(m0)+0][3],0,0,0); \
        acc[(m0)+1][0] = __builtin_amdgcn_mfma_f32_16x16x32_bf16(af1, b0, acc[(m0)+1][0],0,0,0); \
        acc[(m0)+1][1] = __builtin_amdgcn_mfma_f32_16x16x32_bf16(af1, b1, acc[(m0)+1][1],0,0,0); \
        acc[(m0)+1][2] = __builtin_amdgcn_mfma_f32_16x16x32_bf16(af1, b2, acc[(m0)+1][2],0,0,0); \
        acc[(m0)+1][3] = __builtin_amdgcn_mfma_f32_16x16x32_bf16(af1, b3, acc[(m0)+1][3],0,0,0); \
        acc[(m0)+2][0] = __builtin_amdgcn_mfma_f32_16x16x32_bf16(af2, b0, acc[(m0)+2][0],0,0,0); \
        acc[(m0)+2][1] = __builtin_amdgcn_mfma_f32_16x16x32_bf16(af2, b1, acc[(m0)+2][1],0,0,0); \
        acc[(m0)+2][2] = __builtin_amdgcn_mfma_f32_16x16x32_bf16(af2, b2, acc[(m0)+2][2],0,0,0); \
        acc[(m0)+2][3] = __builtin_amdgcn_mfma_f32_16x16x32_bf16(af2, b3, acc[(m0)+2][3],0,0,0); \
        acc[(m0)+3][0] = __builtin_amdgcn_mfma_f32_16x16x32_bf16(af3, b0, acc[(m0)+3][0],0,0,0); \
        acc[(m0)+3][1] = __builtin_amdgcn_mfma_f32_16x16x32_bf16(af3, b1, acc[(m0)+3][1],0,0,0); \
        acc[(m0)+3][2] = __builtin_amdgcn_mfma_f32_16x16x32_bf16(af3, b2, acc[(m0)+3][2],0,0,0); \
        acc[(m0)+3][3] = __builtin_amdgcn_mfma_f32_16x16x32_bf16(af3, b3, acc[(m0)+3][3],0,0,0); \
        __builtin_amdgcn_s_setprio(0);                                                  \
        EXTRA;                                                                          \
        __builtin_amdgcn_s_barrier();                                                   \
    } while (0)

    __syncthreads();          // publish XR copies (drains staging ds_writes)

    // prologue: stage chunks c0, c1 fully (8 loads in flight)
    #pragma unroll
    for (int q = 0; q < 4; ++q) STAGE1(0, rot, q);
    {
        const int c1 = (rot + 1) & 31;
        #pragma unroll
        for (int q = 0; q < 4; ++q) STAGE1(SA_BUF, c1, q);
    }

    LOADB4(rot * 2);          // B frags for first chunk

    asm volatile("s_waitcnt vmcnt(4)" ::: "memory");   // chunk c0 landed
    __builtin_amdgcn_sched_barrier(0);
    __builtin_amdgcn_s_barrier();

    int curBase = 0;
    int stBase  = 2 * SA_BUF;
    for (int c = 0; c < 32; ++c) {
        const int chunk   = (c + rot) & 31;
        const int nchunk  = (c + 1 + rot) & 31;
        const int stChunk = (c + 2 + rot) & 31;   // dead re-fetch at tail: harmless

        PHASE(0, swz0, 0, ((void)0));
        PHASE(4, swz0, 1, ROLLB(chunk * 2 + 1));
        PHASE(0, swz1, 2, ((void)0));
        PHASE(4, swz1, 3, {
            if (nchunk == 0) { LOADB4(0); }          // wrap (or dead tail)
            else             { ROLLB(nchunk * 2); }
            asm volatile("s_waitcnt vmcnt(4)" ::: "memory");   // next chunk ready
            __builtin_amdgcn_sched_barrier(0);
        });

        curBase += SA_BUF; if (curBase == 3 * SA_BUF) curBase = 0;
        stBase  += SA_BUF; if (stBase  == 3 * SA_BUF) stBase  = 0;
    }
    #undef PHASE
    #undef LOADB
    #undef LOADB4
    #undef ROLLB
    #undef STAGE1

    // ---- threshold + candidate append ----
    const float sig = sqrtf((hdr[2] * (1.0f / (float)NA)) * (hdr[b] * (1.0f / (float)NS)));
    const float T0  = 3.35f * sig;   // cutoff ~4sigma; bf16 noise ~0.006sigma

    #pragma unroll
    for (int mi = 0; mi < 8; ++mi) {
        #pragma unroll
        for (int ni = 0; ni < 4; ++ni) {
            #pragma unroll
            for (int r = 0; r < 4; ++r) {
                float v = acc[mi][ni][r];
                if (v > T0) {
                    unsigned a = (unsigned)(a0 + wm * 128 + mi * 16 + g * 4 + r);
                    unsigned t = (unsigned)(t0 + wn * 64 + ni * 16 + ln);
                    unsigned idx = (a << 15) | t;
                    unsigned pos = atomicAdd(&candCnt[b], 1u);
                    if (pos < cap) {
                        Cand cc; cc.v = v; cc.idx = idx;
                        cand[(size_t)b * cap + pos] = cc;
                    }
                }
            }
        }
    }
}

// ---------------------------------------------------------------------------
// Exact fp64 re-evaluation of each candidate (selection authority).
// ---------------------------------------------------------------------------
__global__ void refine_kernel(const float* __restrict__ x, const float* __restrict__ atoms,
                              const unsigned* __restrict__ candCnt, Cand* __restrict__ cand,
                              unsigned cap) {
    const int lane = threadIdx.x & 63;
    const int wid  = (int)((blockIdx.x * blockDim.x + threadIdx.x) >> 6);
    const int nw   = (int)((gridDim.x * blockDim.x) >> 6);
    const int n0 = (int)min(candCnt[0], cap);
    const int n1 = (int)min(candCnt[1], cap);
    const int total = n0 + n1;
    for (int c = wid; c < total; c += nw) {
        const int b = (c < n0) ? 0 : 1;
        const size_t ci = (c < n0) ? (size_t)c : ((size_t)cap + (size_t)(c - n0));
        const unsigned idx = cand[ci].idx;
        const int a = (int)(idx >> 15);
        const int t = (int)(idx & (NS - 1));
        const float* __restrict__ ar = atoms + (size_t)a * AL;
        const float* __restrict__ xr = x + b * NS;
        double s = 0.0;
        for (int k = lane; k < AL; k += 64) {
            int xi = t - k;
            if (xi >= 0) s += (double)ar[k] * (double)xr[xi];
        }
        #pragma unroll
        for (int o = 32; o >= 1; o >>= 1) s += __shfl_down(s, o);
        if (lane == 0) cand[ci].v = (float)s;
    }
}

// ---------------------------------------------------------------------------
// Exact top-KKEEP among candidates (binary search on threshold; ties by
// ascending flat index = jax.lax.top_k semantics). One block per batch.
// Candidate values cached in LDS for the search sweeps.
// ---------------------------------------------------------------------------
#define SELCAP 16384

__global__ void select_kernel(const unsigned* __restrict__ candCnt,
                              const Cand* __restrict__ cand, Cand* __restrict__ sel,
                              unsigned cap) {
    __shared__ float    s_vals[SELCAP];
    __shared__ float    s_red[16];
    __shared__ int      s_cnt;
    __shared__ int      s_nA;
    __shared__ int      s_nT;
    __shared__ int      s_exact;
    __shared__ float    s_tau;
    __shared__ Cand     s_A[KKEEP];
    __shared__ unsigned s_T[256];

    const int b = blockIdx.x;
    const Cand* __restrict__ cb = cand + (size_t)b * cap;
    const int n   = (int)min(candCnt[b], cap);
    const int tid = threadIdx.x;

    if (n <= KKEEP) {   // statistically unreachable; safe fallback
        for (int i = tid; i < KKEEP; i += blockDim.x) {
            Cand z; z.v = 0.f; z.idx = 0u;
            sel[b * KKEEP + i] = (i < n) ? cb[i] : z;
        }
        return;
    }

    const bool useLds = (n <= SELCAP);
    if (useLds)
        for (int i = tid; i < n; i += blockDim.x) s_vals[i] = cb[i].v;

    float m = 0.f;
    if (useLds) { __syncthreads();
        for (int i = tid; i < n; i += blockDim.x) m = fmaxf(m, s_vals[i]);
    } else {
        for (int i = tid; i < n; i += blockDim.x) m = fmaxf(m, cb[i].v);
    }
    #pragma unroll
    for (int o = 32; o >= 1; o >>= 1) m = fmaxf(m, __shfl_down(m, o));
    if ((tid & 63) == 0) s_red[tid >> 6] = m;
    if (tid == 0) s_exact = 0;
    __syncthreads();
    float hi;
    {
        float mm = 0.f;
        #pragma unroll
        for (int w = 0; w < 16; ++w) mm = fmaxf(mm, s_red[w]);
        hi = mm;
    }
    float lo = 0.f;
    for (int iter = 0; iter < 64; ++iter) {
        float mid = 0.5f * (lo + hi);
        if (!(mid > lo && mid < hi)) break;
        if (tid == 0) s_cnt = 0;
        __syncthreads();
        int c = 0;
        if (useLds) for (int i = tid; i < n; i += blockDim.x) c += (s_vals[i] > mid) ? 1 : 0;
        else        for (int i = tid; i < n; i += blockDim.x) c += (cb[i].v  > mid) ? 1 : 0;
        #pragma unroll
        for (int o = 32; o >= 1; o >>= 1) c += __shfl_down(c, o);
        if ((tid & 63) == 0) atomicAdd(&s_cnt, c);
        __syncthreads();
        int cm = s_cnt;
        __syncthreads();
        if (cm == KKEEP) { if (tid == 0) { s_tau = mid; s_exact = 1; } break; }
        if (cm > KKEEP) lo = mid; else hi = mid;
    }
    __syncthreads();

    const int   exact = s_exact;
    const float tau   = exact ? s_tau : hi;

    for (int i = tid; i < KKEEP; i += blockDim.x) { s_A[i].v = 0.f; s_A[i].idx = 0u; }
    if (tid == 0) { s_nA = 0; s_nT = 0; }
    __syncthreads();

    for (int i = tid; i < n; i += blockDim.x) {
        float v = cb[i].v;
        if (v > tau) {
            int p = atomicAdd(&s_nA, 1);
            if (p < KKEEP) s_A[p] = cb[i];
        } else if (!exact && v == tau) {
            int p = atomicAdd(&s_nT, 1);
            if (p < 256) s_T[p] = cb[i].idx;
        }
    }
    __syncthreads();
    if (tid == 0) {
        int nA = s_nA; if (nA > KKEEP) nA = KKEEP;
        int need = KKEEP - nA;
        int nT = s_nT; if (nT > 256) nT = 256;
        for (int r = 0; r < need && r < nT; ++r) {
            unsigned best = 0xffffffffu; int bj = -1;
            for (int j = 0; j < nT; ++j) if (s_T[j] < best) { best = s_T[j]; bj = j; }
            Cand c; c.v = tau; c.idx = best;
            s_A[nA + r] = c;
            if (bj >= 0) s_T[bj] = 0xffffffffu;
        }
    }
    __syncthreads();
    for (int i = tid; i < KKEEP; i += blockDim.x) sel[b * KKEEP + i] = s_A[i];
}

// ---------------------------------------------------------------------------
// recon[b,t] = sum_e val_e * atoms[a_e, t - t0_e]  (gather, deterministic
// within threshold).  Per-segment filter: only ~72 of 1024 entries touch a
// 256-sample segment -> compact LDS list first, then the FMA loop.
// ---------------------------------------------------------------------------
__global__ void recon_kernel(const float* __restrict__ atoms, const Cand* __restrict__ sel,
                             float* __restrict__ out) {
    __shared__ float s_cv[KKEEP];
    __shared__ int   s_ca[KKEEP];
    __shared__ int   s_ct[KKEEP];
    __shared__ int   s_n;
    const int b    = blockIdx.x >> 7;                    // 128 blocks per batch
    const int tseg = (blockIdx.x & 127) << 8;
    const int t    = tseg + threadIdx.x;
    if (threadIdx.x == 0) s_n = 0;
    __syncthreads();
    for (int i = threadIdx.x; i < KKEEP; i += blockDim.x) {
        Cand c = sel[b * KKEEP + i];
        int t0e = (int)(c.idx & (NS - 1));
        // eligible iff [t0e, t0e+AL-1] intersects [tseg, tseg+255]
        if (c.v != 0.f && t0e <= tseg + 255 && t0e + (AL - 1) >= tseg) {
            int p = atomicAdd(&s_n, 1);
            s_cv[p] = c.v;
            s_ca[p] = (int)(c.idx >> 15);
            s_ct[p] = t0e;
        }
    }
    __syncthreads();
    const int n = s_n;
    float acc = 0.f;
    for (int e = 0; e < n; ++e) {
        int d = t - s_ct[e];
        if ((unsigned)d < (unsigned)AL)
            acc += s_cv[e] * atoms[(size_t)s_ca[e] * AL + d];
    }
    out[b * NS + t] = acc;
}

extern "C" void kernel_launch(void* const* d_in, const int* in_sizes, int n_in,
                              void* d_out, int out_size, void* d_ws, size_t ws_size,
                              hipStream_t stream) {
    const float* x     = (const float*)d_in[0];   // (2,1,32768)
    const float* atoms = (const float*)d_in[1];   // (1,1024,2048)
    float* out = (float*)d_out;                   // (2,1,32768)

    float*          hdr     = (float*)d_ws;
    unsigned*       candCnt = (unsigned*)((char*)d_ws + 16);
    Cand*           sel     = (Cand*)((char*)d_ws + 64);
    unsigned short* ab16    = (unsigned short*)((char*)d_ws + 65536);
    const size_t    candOff = 65536 + (size_t)NA * AL * 2;   // 4,259,840
    Cand*           cand    = (Cand*)((char*)d_ws + candOff);

    unsigned cap = CAPC;
    if (ws_size > candOff + 2 * sizeof(Cand) * 1024) {
        size_t fit = (ws_size - candOff) / (2 * sizeof(Cand));
        if (fit < cap) cap = (unsigned)fit;
    } else {
        cap = 1024;
    }

    hipMemsetAsync(d_ws, 0, 256, stream);  // hdr + counters
    sums_kernel     <<<512, 256, 0, stream>>>(x, atoms, hdr);
    cvt_atoms_kernel<<<(NA * AL) / (256 * 4), 256, 0, stream>>>(atoms, ab16);
    fm_kernel       <<<2 * (NA / 256) * (NS / 256), 512, 0, stream>>>(x, ab16, hdr, candCnt, cand, cap);
    refine_kernel   <<<2048, 256, 0, stream>>>(x, atoms, candCnt, cand, cap);
    select_kernel   <<<2, 1024, 0, stream>>>(candCnt, cand, sel, cap);
    recon_kernel    <<<256, 256, 0, stream>>>(atoms, sel, out);
}